// Round 1
// baseline (317.843 us; speedup 1.0000x reference)
//
#include <hip/hip_runtime.h>

// Problem constants
#define BB    8
#define NBB   1024
#define KK    9
#define CC    32
#define CMM   128
#define NTOT  (BB*NBB)        // 8192
#define MM    (NBB*KK)        // 9216 per batch
#define MSPLIT 4
#define MRANGE (MM/MSPLIT)    // 2304
#define MC    32              // m-chunk per LDS stage
#define TN    128             // n-rows per block in k_sample
#define NEG   0.01f
#define EPS   1e-5f

// Workspace layout (floats)
#define OFF_CONVW 0
#define SZ_CONVW  (NTOT*KK*CC)            // 2359296
#define OFF_PART  (OFF_CONVW + SZ_CONVW)
#define SZ_ONE    (NTOT*CC)               // 262144
#define SZ_PART   (MSPLIT*SZ_ONE)
#define OFF_X0    (OFF_PART + SZ_PART)
#define OFF_X     (OFF_X0 + SZ_ONE)
#define OFF_H0    (OFF_X + SZ_ONE)
#define SZ_H0     (NTOT*CMM)
#define OFF_S1    (OFF_H0 + SZ_H0)        // 64 floats: sum[32], sumsq[32]
#define OFF_S2    (OFF_S1 + 64)           // 256 floats: sum[128], sumsq[128]

// ---------------------------------------------------------------------------
// Kernel A: conv_w[n][k][c] = sum_c' weights[n][c'] * kw[k][c'][c]
// ---------------------------------------------------------------------------
__global__ __launch_bounds__(256) void k_convw(const float* __restrict__ w,
                                               const float* __restrict__ kw,
                                               float* __restrict__ convw) {
    __shared__ __align__(16) float kwl[KK*CC*CC];  // 9216 floats
    __shared__ __align__(16) float wl[32*CC];
    int t = threadIdx.x;
    for (int i = t; i < KK*CC*CC; i += 256) kwl[i] = kw[i];
    int row0 = blockIdx.x * 32;
    for (int i = t; i < 32*CC; i += 256) wl[i] = w[(size_t)row0*CC + i];
    __syncthreads();
    int c = t & 31, rs = t >> 5;
    for (int ri = 0; ri < 4; ++ri) {
        int r = rs + 8*ri;
        #pragma unroll
        for (int k = 0; k < KK; ++k) {
            float acc = 0.f;
            #pragma unroll
            for (int cp = 0; cp < CC; ++cp)
                acc = fmaf(wl[r*CC+cp], kwl[(k*CC+cp)*CC + c], acc);
            convw[((size_t)(row0 + r)*KK + k)*CC + c] = acc;
        }
    }
}

// ---------------------------------------------------------------------------
// Kernel B (dominant): partial[ms][n][c] = sum_{m in range}
//      exp(-2*|p_n - (p_{m/9} + kp_{m%9})|^2) * conv_w[m][c]
// block = (b, ntile, msplit); 256 threads; 128 rows x 2304 m per block.
// ---------------------------------------------------------------------------
__global__ __launch_bounds__(256) void k_sample(const float* __restrict__ pos,
                                                const float* __restrict__ kpos,
                                                const float* __restrict__ convw,
                                                float* __restrict__ part) {
    __shared__ __align__(16) float cw[MC*CC];     // 1024 floats
    __shared__ __align__(16) float el[MC*132];    // 4224 floats (padded stride)
    __shared__ __align__(16) float pl[TN*2];
    __shared__ float kpl[KK*2];

    int t = threadIdx.x;
    int blk = blockIdx.x;
    int ms = blk & 3;
    int nt = (blk >> 2) & 7;
    int b  = blk >> 5;
    int rowbase = b*NBB + nt*TN;  // global row of first row in tile

    if (t < TN*2) pl[t] = pos[(size_t)rowbase*2 + t];
    if (t < KK*2) kpl[t] = kpos[t];

    float acc[4][4];
    #pragma unroll
    for (int i = 0; i < 4; ++i)
        #pragma unroll
        for (int j = 0; j < 4; ++j) acc[i][j] = 0.f;

    int cg = t & 7, rs = t >> 3;        // MAC-phase mapping
    int rlane = t & 31, mgrp = t >> 5;  // exp-phase mapping
    const float LOG2E2 = -2.8853900817779268f;  // -2/ln(2)... = -2*log2(e)

    for (int ch = 0; ch < MRANGE/MC; ++ch) {
        int m0 = ms*MRANGE + ch*MC;
        __syncthreads();  // protect cw/el reuse; first iter covers pl/kpl
        // stage conv_w chunk: 1024 floats, one float4 per thread
        {
            const float4* src = (const float4*)(convw + ((size_t)b*MM + m0)*CC);
            ((float4*)cw)[t] = src[t];
        }
        // exp phase: each thread: 4 m's x 4 rows
        #pragma unroll
        for (int mj = 0; mj < 4; ++mj) {
            int ml = mgrp + 8*mj;
            int m = m0 + ml;
            int np = m / 9;
            int k = m - np*9;
            float qx = pos[(size_t)(b*NBB + np)*2 + 0] + kpl[2*k];
            float qy = pos[(size_t)(b*NBB + np)*2 + 1] + kpl[2*k+1];
            #pragma unroll
            for (int ri = 0; ri < 4; ++ri) {
                int r = rlane + 32*ri;
                float dx = pl[2*r]   - qx;
                float dy = pl[2*r+1] - qy;
                float d2 = fmaf(dx, dx, dy*dy);
                el[ml*132 + r] = exp2f(LOG2E2 * d2);
            }
        }
        __syncthreads();
        // MAC phase: 4 rows x 4 channels per thread
        #pragma unroll 8
        for (int m = 0; m < MC; ++m) {
            float4 w4 = *(const float4*)&cw[m*CC + (cg<<2)];
            float4 e4 = *(const float4*)&el[m*132 + (rs<<2)];
            acc[0][0] = fmaf(e4.x, w4.x, acc[0][0]);
            acc[0][1] = fmaf(e4.x, w4.y, acc[0][1]);
            acc[0][2] = fmaf(e4.x, w4.z, acc[0][2]);
            acc[0][3] = fmaf(e4.x, w4.w, acc[0][3]);
            acc[1][0] = fmaf(e4.y, w4.x, acc[1][0]);
            acc[1][1] = fmaf(e4.y, w4.y, acc[1][1]);
            acc[1][2] = fmaf(e4.y, w4.z, acc[1][2]);
            acc[1][3] = fmaf(e4.y, w4.w, acc[1][3]);
            acc[2][0] = fmaf(e4.z, w4.x, acc[2][0]);
            acc[2][1] = fmaf(e4.z, w4.y, acc[2][1]);
            acc[2][2] = fmaf(e4.z, w4.z, acc[2][2]);
            acc[2][3] = fmaf(e4.z, w4.w, acc[2][3]);
            acc[3][0] = fmaf(e4.w, w4.x, acc[3][0]);
            acc[3][1] = fmaf(e4.w, w4.y, acc[3][1]);
            acc[3][2] = fmaf(e4.w, w4.z, acc[3][2]);
            acc[3][3] = fmaf(e4.w, w4.w, acc[3][3]);
        }
    }
    // write partials (deterministic, no atomics)
    float* dst = part + (size_t)ms*SZ_ONE;
    #pragma unroll
    for (int i = 0; i < 4; ++i) {
        int r = rowbase + rs*4 + i;
        float4 v = make_float4(acc[i][0], acc[i][1], acc[i][2], acc[i][3]);
        *(float4*)&dst[(size_t)r*CC + (cg<<2)] = v;
    }
}

// ---------------------------------------------------------------------------
// Kernel B2: x0 = leaky(sum of partials); accumulate per-channel sum/sumsq
// ---------------------------------------------------------------------------
__global__ __launch_bounds__(256) void k_leaky_stats(const float* __restrict__ part,
                                                     float* __restrict__ x0,
                                                     float* __restrict__ s1) {
    __shared__ float ss[32], sq[32];
    int t = threadIdx.x;
    if (t < 32) { ss[t] = 0.f; sq[t] = 0.f; }
    __syncthreads();
    float lsum = 0.f, lsq = 0.f;
    int base = blockIdx.x * 2048;
    for (int j = 0; j < 8; ++j) {
        int idx = base + j*256 + t;
        float v = part[idx] + part[SZ_ONE + idx] + part[2*SZ_ONE + idx] + part[3*SZ_ONE + idx];
        v = v >= 0.f ? v : NEG*v;
        x0[idx] = v;
        lsum += v; lsq = fmaf(v, v, lsq);
    }
    atomicAdd(&ss[t & 31], lsum);
    atomicAdd(&sq[t & 31], lsq);
    __syncthreads();
    if (t < 32) { atomicAdd(&s1[t], ss[t]); atomicAdd(&s1[32+t], sq[t]); }
}

// ---------------------------------------------------------------------------
// Kernel C: x = bn1(x0) + weights (store); h0 = leaky(x @ W1 + b1) (store);
//           accumulate bn2 stats.  64 rows per block.
// ---------------------------------------------------------------------------
__global__ __launch_bounds__(256) void k_mlp1(const float* __restrict__ x0,
                                              const float* __restrict__ wts,
                                              const float* __restrict__ gma,
                                              const float* __restrict__ bta,
                                              const float* __restrict__ W1,
                                              const float* __restrict__ b1,
                                              const float* __restrict__ s1,
                                              float* __restrict__ x,
                                              float* __restrict__ h0,
                                              float* __restrict__ s2) {
    __shared__ __align__(16) float xl[64*32];
    __shared__ __align__(16) float w1l[32*CMM];
    int t = threadIdx.x;
    for (int i = t; i < 32*CMM; i += 256) w1l[i] = W1[i];
    int row0 = blockIdx.x * 64;
    for (int i = 0; i < 8; ++i) {
        int idx = i*256 + t;
        int c = idx & 31;
        float mu  = s1[c] * (1.f/NTOT);
        float var = s1[32+c]*(1.f/NTOT) - mu*mu;
        float inv = rsqrtf(var + EPS);
        float v = x0[(size_t)row0*32 + idx];
        v = gma[c]*(v-mu)*inv + bta[c] + wts[(size_t)row0*32 + idx];
        xl[idx] = v;
        x[(size_t)row0*32 + idx] = v;
    }
    __syncthreads();
    int j = t & 127, rh = t >> 7;
    float lsum = 0.f, lsq = 0.f;
    for (int rr = 0; rr < 32; ++rr) {
        int r = rh*32 + rr;
        float acc = b1[j];
        #pragma unroll
        for (int c = 0; c < 32; ++c)
            acc = fmaf(xl[r*32+c], w1l[c*CMM+j], acc);
        acc = acc >= 0.f ? acc : NEG*acc;
        h0[(size_t)(row0+r)*CMM + j] = acc;
        lsum += acc; lsq = fmaf(acc, acc, lsq);
    }
    atomicAdd(&s2[j], lsum);
    atomicAdd(&s2[CMM+j], lsq);
}

// ---------------------------------------------------------------------------
// Kernel D: h = bn2(h0); mlp = h @ W2 + b2; out0 = pos + mlp[:, :2];
//           out1 = x + mlp[:, 2:]. 8 rows per block.
// ---------------------------------------------------------------------------
__global__ __launch_bounds__(256) void k_mlp2(const float* __restrict__ h0,
                                              const float* __restrict__ x,
                                              const float* __restrict__ pos,
                                              const float* __restrict__ g2,
                                              const float* __restrict__ bt2,
                                              const float* __restrict__ W2,
                                              const float* __restrict__ b2,
                                              const float* __restrict__ s2,
                                              float* __restrict__ out) {
    __shared__ __align__(16) float w2l[CMM*34];
    __shared__ __align__(16) float hl[8*CMM];
    __shared__ float mlpd[8*34];
    __shared__ float mu2[CMM], inv2[CMM], g2l[CMM], bt2l[CMM];
    int t = threadIdx.x;
    for (int i = t; i < CMM*34; i += 256) w2l[i] = W2[i];
    if (t < CMM) {
        float mu  = s2[t]*(1.f/NTOT);
        float var = s2[CMM+t]*(1.f/NTOT) - mu*mu;
        mu2[t] = mu; inv2[t] = rsqrtf(var + EPS);
        g2l[t] = g2[t]; bt2l[t] = bt2[t];
    }
    __syncthreads();
    int row0 = blockIdx.x * 8;
    for (int i = 0; i < 4; ++i) {
        int idx = i*256 + t;
        int j = idx & 127, r = idx >> 7;
        float v = h0[(size_t)(row0+r)*CMM + j];
        hl[idx] = g2l[j]*(v-mu2[j])*inv2[j] + bt2l[j];
    }
    __syncthreads();
    int lane = t & 31, r = t >> 5;
    float acc0 = b2[lane];
    float acc1 = (lane < 2) ? b2[32+lane] : 0.f;
    for (int j = 0; j < CMM; ++j) {
        float h = hl[r*CMM + j];
        acc0 = fmaf(h, w2l[j*34 + lane], acc0);
        if (lane < 2) acc1 = fmaf(h, w2l[j*34 + 32 + lane], acc1);
    }
    mlpd[r*34 + lane] = acc0;
    if (lane < 2) mlpd[r*34 + 32 + lane] = acc1;
    __syncthreads();
    int n = row0 + r;
    if (lane < 2)
        out[(size_t)n*2 + lane] = pos[(size_t)n*2 + lane] + mlpd[r*34 + lane];
    out[16384 + (size_t)n*32 + lane] = x[(size_t)n*32 + lane] + mlpd[r*34 + 2 + lane];
}

// ---------------------------------------------------------------------------
extern "C" void kernel_launch(void* const* d_in, const int* in_sizes, int n_in,
                              void* d_out, int out_size, void* d_ws, size_t ws_size,
                              hipStream_t stream) {
    const float* positions = (const float*)d_in[0];
    const float* weights   = (const float*)d_in[1];
    // d_in[2] = batch (int32, all NB) — unused, shapes are static
    const float* kpos = (const float*)d_in[3];
    const float* kw   = (const float*)d_in[4];
    const float* cg   = (const float*)d_in[5];
    const float* cb   = (const float*)d_in[6];
    const float* W1   = (const float*)d_in[7];
    const float* b1   = (const float*)d_in[8];
    const float* bg   = (const float*)d_in[9];
    const float* bb   = (const float*)d_in[10];
    const float* W2   = (const float*)d_in[11];
    const float* b2   = (const float*)d_in[12];
    float* ws  = (float*)d_ws;
    float* out = (float*)d_out;

    // zero the stats accumulators (ws is poisoned 0xAA before every call)
    hipMemsetAsync(ws + OFF_S1, 0, (64 + 256)*sizeof(float), stream);

    k_convw<<<256, 256, 0, stream>>>(weights, kw, ws + OFF_CONVW);
    k_sample<<<256, 256, 0, stream>>>(positions, kpos, ws + OFF_CONVW, ws + OFF_PART);
    k_leaky_stats<<<128, 256, 0, stream>>>(ws + OFF_PART, ws + OFF_X0, ws + OFF_S1);
    k_mlp1<<<128, 256, 0, stream>>>(ws + OFF_X0, weights, cg, cb, W1, b1,
                                    ws + OFF_S1, ws + OFF_X, ws + OFF_H0, ws + OFF_S2);
    k_mlp2<<<1024, 256, 0, stream>>>(ws + OFF_H0, ws + OFF_X, positions,
                                     bg, bb, W2, b2, ws + OFF_S2, out);
}